// Round 3
// baseline (369.192 us; speedup 1.0000x reference)
//
#include <hip/hip_runtime.h>
#include <math.h>

// Fused: per-block 48x48 linear -> (permutation == block re-assembly) ->
// conv1(3->10,5x5)+pool+relu -> conv2(10->20,5x5)+pool+relu -> fc1+relu -> fc2 -> log_softmax
// One workgroup (256 threads) per batch element. All intermediates in LDS.
// Round 3: spill-free phase 1 (chunked k-accumulation, ~30 live VGPRs), LDS aliasing
// (s_h2/s_part/s_f1/s_lg overlay s_img -> 29.2KB, 5 blocks/CU), phase-3 lane=(ci,cjg)
// layout with S2=26 for low-conflict b64 reads, vertical pool via shfl.

#define S1 38               // s_img row stride (floats), plane = 32*S1 = 1216
#define S2 26               // s_h1 row stride (floats), plane = 14*S2 = 364

__global__ __launch_bounds__(256, 5)
void fused_net(const float* __restrict__ x,    // [B,32,32,3] NHWC
               const float* __restrict__ W,    // [48,48]
               const float* __restrict__ w1,   // [10,3,5,5]
               const float* __restrict__ b1,   // [10]
               const float* __restrict__ w2,   // [20,10,5,5]
               const float* __restrict__ b2,   // [20]
               const float* __restrict__ fw1,  // [50,500]
               const float* __restrict__ fb1,  // [50]
               const float* __restrict__ fw2,  // [10,50]
               const float* __restrict__ fb2,  // [10]
               float* __restrict__ out)        // [B,10]
{
    const int b   = blockIdx.x;
    const int tid = threadIdx.x;
    const int wave = __builtin_amdgcn_readfirstlane(tid >> 6);  // uniform -> SGPR weight loads
    const int lane = tid & 63;

    __shared__ __align__(16) float s_img[3 * 32 * S1];   // 14592 B; reused after phase 2
    __shared__ __align__(16) float s_h1[10 * 14 * S2];   // 14560 B
    float* s_h2   = s_img;         // 500 floats (phase >= 3)
    float* s_part = s_img + 512;   // 256
    float* s_f1   = s_img + 768;   // 56
    float* s_lg   = s_img + 832;   // 16

    // ---------------- Phase 1: per-block 48x48 linear -> s_img (NCHW) ----------------
    // lane = block (bi,bj). wave = di (uniform). Chunked over d: 12 x-values + 12 accs live.
    {
        const int bi = lane >> 3, bj = lane & 7;
        const float* xb = x + (size_t)b * 3072 + bi * 384 + bj * 12;
        float acc[3][4];   // [c=gg][dj]
        #pragma unroll
        for (int c = 0; c < 3; ++c)
            #pragma unroll
            for (int dj = 0; dj < 4; ++dj) acc[c][dj] = 0.f;

        #pragma unroll
        for (int d = 0; d < 4; ++d) {
            float xv[12];
            const float4 a0 = *reinterpret_cast<const float4*>(xb + d * 96 + 0);
            const float4 a1 = *reinterpret_cast<const float4*>(xb + d * 96 + 4);
            const float4 a2 = *reinterpret_cast<const float4*>(xb + d * 96 + 8);
            xv[0] = a0.x; xv[1]  = a0.y; xv[2]  = a0.z; xv[3]  = a0.w;
            xv[4] = a1.x; xv[5]  = a1.y; xv[6]  = a1.z; xv[7]  = a1.w;
            xv[8] = a2.x; xv[9]  = a2.y; xv[10] = a2.z; xv[11] = a2.w;
            #pragma unroll
            for (int gg = 0; gg < 3; ++gg) {
                #pragma unroll
                for (int dj = 0; dj < 4; ++dj) {
                    const int kp = wave * 12 + dj * 3 + gg;     // uniform row of W
                    const float* wr = W + kp * 48 + d * 12;
                    #pragma unroll
                    for (int k = 0; k < 12; ++k) acc[gg][dj] += wr[k] * xv[k];
                }
            }
        }
        #pragma unroll
        for (int gg = 0; gg < 3; ++gg) {
            float* dst = &s_img[gg * (32 * S1) + (bi * 4 + wave) * S1 + bj * 4];
            float2 v0; v0.x = acc[gg][0]; v0.y = acc[gg][1];
            float2 v1; v1.x = acc[gg][2]; v1.y = acc[gg][3];
            *reinterpret_cast<float2*>(dst)     = v0;
            *reinterpret_cast<float2*>(dst + 2) = v1;
        }
    }
    __syncthreads();

    // ---------------- Phase 2: conv1 + maxpool + relu -> s_h1 ----------------
    // thread = pooled pixel; rows streamed through a 6-float register window.
    if (tid < 196) {
        const int oi = tid / 14, oj = tid % 14;
        float acc[2][2][10];   // [pi][pj][oc]
        #pragma unroll
        for (int pi = 0; pi < 2; ++pi)
            #pragma unroll
            for (int pj = 0; pj < 2; ++pj)
                #pragma unroll
                for (int o = 0; o < 10; ++o) acc[pi][pj][o] = 0.f;

        const int rbase = (2 * oi) * S1 + 2 * oj;
        for (int ic = 0; ic < 3; ++ic) {
            const float* ip = s_img + ic * (32 * S1) + rbase;
            #pragma unroll
            for (int d = 0; d < 6; ++d) {                  // input row = 2*oi + d
                float wnd[6];
                const float2 r0 = *reinterpret_cast<const float2*>(ip + d * S1 + 0);
                const float2 r1 = *reinterpret_cast<const float2*>(ip + d * S1 + 2);
                const float2 r2 = *reinterpret_cast<const float2*>(ip + d * S1 + 4);
                wnd[0] = r0.x; wnd[1] = r0.y; wnd[2] = r1.x; wnd[3] = r1.y; wnd[4] = r2.x; wnd[5] = r2.y;
                #pragma unroll
                for (int pi = 0; pi < 2; ++pi) {
                    const int ky = d - pi;
                    if (ky < 0 || ky > 4) continue;
                    #pragma unroll
                    for (int kx = 0; kx < 5; ++kx) {
                        float wv[10];
                        #pragma unroll
                        for (int o = 0; o < 10; ++o)
                            wv[o] = w1[o * 75 + ic * 25 + ky * 5 + kx];   // uniform -> SGPR
                        #pragma unroll
                        for (int pj = 0; pj < 2; ++pj)
                            #pragma unroll
                            for (int o = 0; o < 10; ++o)
                                acc[pi][pj][o] += wnd[pj + kx] * wv[o];
                    }
                }
            }
        }
        #pragma unroll
        for (int o = 0; o < 10; ++o) {
            float m = fmaxf(fmaxf(acc[0][0][o], acc[0][1][o]), fmaxf(acc[1][0][o], acc[1][1][o]));
            s_h1[o * (14 * S2) + oi * S2 + oj] = fmaxf(m + b1[o], 0.f);
        }
    }
    __syncthreads();

    // ---------------- Phase 3: conv2 + maxpool + relu -> s_h2 ----------------
    // wave owns ocs 5w..5w+4 (uniform). lane<50: ci=lane/5 (conv row), cjg=lane%5 (pooled col).
    // Lane computes conv pixels (ci, 2cjg) and (ci, 2cjg+1); vertical pool via shfl(lane+5).
    if (lane < 50) {
        const int ci = lane / 5, cjg = lane % 5;
        float acc[2][5];   // [dj][oc]
        #pragma unroll
        for (int dj = 0; dj < 2; ++dj)
            #pragma unroll
            for (int o = 0; o < 5; ++o) acc[dj][o] = 0.f;

        const int rbase = ci * S2 + 2 * cjg;
        for (int ic = 0; ic < 10; ++ic) {
            const float* ip = s_h1 + ic * (14 * S2) + rbase;
            #pragma unroll
            for (int ky = 0; ky < 5; ++ky) {
                float wnd[6];
                const float2 r0 = *reinterpret_cast<const float2*>(ip + ky * S2 + 0);
                const float2 r1 = *reinterpret_cast<const float2*>(ip + ky * S2 + 2);
                const float2 r2 = *reinterpret_cast<const float2*>(ip + ky * S2 + 4);
                wnd[0] = r0.x; wnd[1] = r0.y; wnd[2] = r1.x; wnd[3] = r1.y; wnd[4] = r2.x; wnd[5] = r2.y;
                #pragma unroll
                for (int kx = 0; kx < 5; ++kx) {
                    float wv[5];
                    #pragma unroll
                    for (int o = 0; o < 5; ++o)
                        wv[o] = w2[(wave * 5 + o) * 250 + ic * 25 + ky * 5 + kx]; // uniform
                    #pragma unroll
                    for (int dj = 0; dj < 2; ++dj)
                        #pragma unroll
                        for (int o = 0; o < 5; ++o)
                            acc[dj][o] += wnd[dj + kx] * wv[o];
                }
            }
        }
        // horizontal pool in-lane; vertical pool with row partner (lane+5); bias after max.
        #pragma unroll
        for (int o = 0; o < 5; ++o) {
            const float pm = fmaxf(acc[0][o], acc[1][o]);
            const float om = __shfl(pm, lane + 5, 64);
            if ((ci & 1) == 0) {
                const float v = fmaxf(pm, om) + b2[wave * 5 + o];
                s_h2[(wave * 5 + o) * 25 + (ci >> 1) * 5 + cjg] = fmaxf(v, 0.f);
            }
        }
    }
    __syncthreads();

    // ---------------- Phase 4: fc1 (500->50) split 5-way + relu ----------------
    if (tid < 250) {
        const int oc = tid / 5, part = tid % 5;
        const float* wr = fw1 + oc * 500 + part * 100;
        const float* hp = s_h2 + part * 100;
        float a = 0.f;
        #pragma unroll
        for (int i = 0; i < 25; ++i) {
            const float4 wv = *reinterpret_cast<const float4*>(wr + i * 4);
            const float4 hv = *reinterpret_cast<const float4*>(hp + i * 4);
            a += wv.x * hv.x + wv.y * hv.y + wv.z * hv.z + wv.w * hv.w;
        }
        s_part[tid] = a;
    }
    __syncthreads();
    if (tid < 50) {
        float a = fb1[tid];
        #pragma unroll
        for (int j = 0; j < 5; ++j) a += s_part[tid * 5 + j];
        s_f1[tid] = fmaxf(a, 0.f);
    }
    __syncthreads();

    // ---------------- Phase 5: fc2 (50->10) ----------------
    if (tid < 10) {
        const float* wr = fw2 + tid * 50;
        float a = fb2[tid];
        for (int k = 0; k < 50; ++k) a += s_f1[k] * wr[k];
        s_lg[tid] = a;
    }
    __syncthreads();

    // ---------------- Phase 6: log_softmax ----------------
    if (tid < 10) {
        float m = s_lg[0];
        for (int k = 1; k < 10; ++k) m = fmaxf(m, s_lg[k]);
        float s = 0.f;
        for (int k = 0; k < 10; ++k) s += expf(s_lg[k] - m);
        out[(size_t)b * 10 + tid] = s_lg[tid] - m - logf(s);
    }
}

extern "C" void kernel_launch(void* const* d_in, const int* in_sizes, int n_in,
                              void* d_out, int out_size, void* d_ws, size_t ws_size,
                              hipStream_t stream) {
    const float* x   = (const float*)d_in[0];
    const float* W   = (const float*)d_in[1];
    const float* w1  = (const float*)d_in[2];
    const float* b1  = (const float*)d_in[3];
    const float* w2  = (const float*)d_in[4];
    const float* b2  = (const float*)d_in[5];
    const float* fw1 = (const float*)d_in[6];
    const float* fb1 = (const float*)d_in[7];
    const float* fw2 = (const float*)d_in[8];
    const float* fb2 = (const float*)d_in[9];
    float* o = (float*)d_out;

    const int B = in_sizes[0] / 3072;
    fused_net<<<dim3(B), dim3(256), 0, stream>>>(x, W, w1, b1, w2, b2, fw1, fb1, fw2, fb2, o);
}

// Round 4
// 328.476 us; speedup vs baseline: 1.1240x; 1.1240x over previous
//
#include <hip/hip_runtime.h>
#include <math.h>

// Fused: per-block 48x48 linear -> (permutation == block re-assembly) ->
// conv1(3->10,5x5)+pool+relu -> conv2(10->20,5x5)+pool+relu -> fc1+relu -> fc2 -> log_softmax
// One workgroup (256 threads) per batch element. All intermediates in LDS.
// Round 4: drop the min-waves launch-bounds clause. (256,5) capped the allocator at 48
// VGPRs and spilled phase 2's 40 accumulators to scratch (35 MB/dispatch WRITE_SIZE).
// __launch_bounds__(256) alone lifts the cap to 256 VGPR; occupancy becomes LDS-limited
// (29.2 KB -> 5 blocks/CU) instead of spill-crippled.

#define S1 38               // s_img row stride (floats), plane = 32*S1 = 1216
#define S2 26               // s_h1 row stride (floats), plane = 14*S2 = 364

__global__ __launch_bounds__(256)
void fused_net(const float* __restrict__ x,    // [B,32,32,3] NHWC
               const float* __restrict__ W,    // [48,48]
               const float* __restrict__ w1,   // [10,3,5,5]
               const float* __restrict__ b1,   // [10]
               const float* __restrict__ w2,   // [20,10,5,5]
               const float* __restrict__ b2,   // [20]
               const float* __restrict__ fw1,  // [50,500]
               const float* __restrict__ fb1,  // [50]
               const float* __restrict__ fw2,  // [10,50]
               const float* __restrict__ fb2,  // [10]
               float* __restrict__ out)        // [B,10]
{
    const int b   = blockIdx.x;
    const int tid = threadIdx.x;
    const int wave = __builtin_amdgcn_readfirstlane(tid >> 6);  // uniform -> SGPR weight loads
    const int lane = tid & 63;

    __shared__ __align__(16) float s_img[3 * 32 * S1];   // 14592 B; reused after phase 2
    __shared__ __align__(16) float s_h1[10 * 14 * S2];   // 14560 B
    float* s_h2   = s_img;         // 500 floats (phase >= 3)
    float* s_part = s_img + 512;   // 256
    float* s_f1   = s_img + 768;   // 56
    float* s_lg   = s_img + 832;   // 16

    // ---------------- Phase 1: per-block 48x48 linear -> s_img (NCHW) ----------------
    // lane = block (bi,bj). wave = di (uniform). Chunked over d: 12 x-values + 12 accs live.
    {
        const int bi = lane >> 3, bj = lane & 7;
        const float* xb = x + (size_t)b * 3072 + bi * 384 + bj * 12;
        float acc[3][4];   // [c=gg][dj]
        #pragma unroll
        for (int c = 0; c < 3; ++c)
            #pragma unroll
            for (int dj = 0; dj < 4; ++dj) acc[c][dj] = 0.f;

        #pragma unroll
        for (int d = 0; d < 4; ++d) {
            float xv[12];
            const float4 a0 = *reinterpret_cast<const float4*>(xb + d * 96 + 0);
            const float4 a1 = *reinterpret_cast<const float4*>(xb + d * 96 + 4);
            const float4 a2 = *reinterpret_cast<const float4*>(xb + d * 96 + 8);
            xv[0] = a0.x; xv[1]  = a0.y; xv[2]  = a0.z; xv[3]  = a0.w;
            xv[4] = a1.x; xv[5]  = a1.y; xv[6]  = a1.z; xv[7]  = a1.w;
            xv[8] = a2.x; xv[9]  = a2.y; xv[10] = a2.z; xv[11] = a2.w;
            #pragma unroll
            for (int gg = 0; gg < 3; ++gg) {
                #pragma unroll
                for (int dj = 0; dj < 4; ++dj) {
                    const int kp = wave * 12 + dj * 3 + gg;     // uniform row of W
                    const float* wr = W + kp * 48 + d * 12;
                    #pragma unroll
                    for (int k = 0; k < 12; ++k) acc[gg][dj] += wr[k] * xv[k];
                }
            }
        }
        #pragma unroll
        for (int gg = 0; gg < 3; ++gg) {
            float* dst = &s_img[gg * (32 * S1) + (bi * 4 + wave) * S1 + bj * 4];
            float2 v0; v0.x = acc[gg][0]; v0.y = acc[gg][1];
            float2 v1; v1.x = acc[gg][2]; v1.y = acc[gg][3];
            *reinterpret_cast<float2*>(dst)     = v0;
            *reinterpret_cast<float2*>(dst + 2) = v1;
        }
    }
    __syncthreads();

    // ---------------- Phase 2: conv1 + maxpool + relu -> s_h1 ----------------
    // thread = pooled pixel; rows streamed through a 6-float register window.
    if (tid < 196) {
        const int oi = tid / 14, oj = tid % 14;
        float acc[2][2][10];   // [pi][pj][oc]
        #pragma unroll
        for (int pi = 0; pi < 2; ++pi)
            #pragma unroll
            for (int pj = 0; pj < 2; ++pj)
                #pragma unroll
                for (int o = 0; o < 10; ++o) acc[pi][pj][o] = 0.f;

        const int rbase = (2 * oi) * S1 + 2 * oj;
        for (int ic = 0; ic < 3; ++ic) {
            const float* ip = s_img + ic * (32 * S1) + rbase;
            #pragma unroll
            for (int d = 0; d < 6; ++d) {                  // input row = 2*oi + d
                float wnd[6];
                const float2 r0 = *reinterpret_cast<const float2*>(ip + d * S1 + 0);
                const float2 r1 = *reinterpret_cast<const float2*>(ip + d * S1 + 2);
                const float2 r2 = *reinterpret_cast<const float2*>(ip + d * S1 + 4);
                wnd[0] = r0.x; wnd[1] = r0.y; wnd[2] = r1.x; wnd[3] = r1.y; wnd[4] = r2.x; wnd[5] = r2.y;
                #pragma unroll
                for (int pi = 0; pi < 2; ++pi) {
                    const int ky = d - pi;
                    if (ky < 0 || ky > 4) continue;
                    #pragma unroll
                    for (int kx = 0; kx < 5; ++kx) {
                        float wv[10];
                        #pragma unroll
                        for (int o = 0; o < 10; ++o)
                            wv[o] = w1[o * 75 + ic * 25 + ky * 5 + kx];   // uniform -> SGPR
                        #pragma unroll
                        for (int pj = 0; pj < 2; ++pj)
                            #pragma unroll
                            for (int o = 0; o < 10; ++o)
                                acc[pi][pj][o] += wnd[pj + kx] * wv[o];
                    }
                }
            }
        }
        #pragma unroll
        for (int o = 0; o < 10; ++o) {
            float m = fmaxf(fmaxf(acc[0][0][o], acc[0][1][o]), fmaxf(acc[1][0][o], acc[1][1][o]));
            s_h1[o * (14 * S2) + oi * S2 + oj] = fmaxf(m + b1[o], 0.f);
        }
    }
    __syncthreads();

    // ---------------- Phase 3: conv2 + maxpool + relu -> s_h2 ----------------
    // wave owns ocs 5w..5w+4 (uniform). lane<50: ci=lane/5 (conv row), cjg=lane%5 (pooled col).
    // Lane computes conv pixels (ci, 2cjg) and (ci, 2cjg+1); vertical pool via shfl(lane+5).
    if (lane < 50) {
        const int ci = lane / 5, cjg = lane % 5;
        float acc[2][5];   // [dj][oc]
        #pragma unroll
        for (int dj = 0; dj < 2; ++dj)
            #pragma unroll
            for (int o = 0; o < 5; ++o) acc[dj][o] = 0.f;

        const int rbase = ci * S2 + 2 * cjg;
        for (int ic = 0; ic < 10; ++ic) {
            const float* ip = s_h1 + ic * (14 * S2) + rbase;
            #pragma unroll
            for (int ky = 0; ky < 5; ++ky) {
                float wnd[6];
                const float2 r0 = *reinterpret_cast<const float2*>(ip + ky * S2 + 0);
                const float2 r1 = *reinterpret_cast<const float2*>(ip + ky * S2 + 2);
                const float2 r2 = *reinterpret_cast<const float2*>(ip + ky * S2 + 4);
                wnd[0] = r0.x; wnd[1] = r0.y; wnd[2] = r1.x; wnd[3] = r1.y; wnd[4] = r2.x; wnd[5] = r2.y;
                #pragma unroll
                for (int kx = 0; kx < 5; ++kx) {
                    float wv[5];
                    #pragma unroll
                    for (int o = 0; o < 5; ++o)
                        wv[o] = w2[(wave * 5 + o) * 250 + ic * 25 + ky * 5 + kx]; // uniform
                    #pragma unroll
                    for (int dj = 0; dj < 2; ++dj)
                        #pragma unroll
                        for (int o = 0; o < 5; ++o)
                            acc[dj][o] += wnd[dj + kx] * wv[o];
                }
            }
        }
        // horizontal pool in-lane; vertical pool with row partner (lane+5); bias after max.
        #pragma unroll
        for (int o = 0; o < 5; ++o) {
            const float pm = fmaxf(acc[0][o], acc[1][o]);
            const float om = __shfl(pm, lane + 5, 64);
            if ((ci & 1) == 0) {
                const float v = fmaxf(pm, om) + b2[wave * 5 + o];
                s_h2[(wave * 5 + o) * 25 + (ci >> 1) * 5 + cjg] = fmaxf(v, 0.f);
            }
        }
    }
    __syncthreads();

    // ---------------- Phase 4: fc1 (500->50) split 5-way + relu ----------------
    if (tid < 250) {
        const int oc = tid / 5, part = tid % 5;
        const float* wr = fw1 + oc * 500 + part * 100;
        const float* hp = s_h2 + part * 100;
        float a = 0.f;
        #pragma unroll
        for (int i = 0; i < 25; ++i) {
            const float4 wv = *reinterpret_cast<const float4*>(wr + i * 4);
            const float4 hv = *reinterpret_cast<const float4*>(hp + i * 4);
            a += wv.x * hv.x + wv.y * hv.y + wv.z * hv.z + wv.w * hv.w;
        }
        s_part[tid] = a;
    }
    __syncthreads();
    if (tid < 50) {
        float a = fb1[tid];
        #pragma unroll
        for (int j = 0; j < 5; ++j) a += s_part[tid * 5 + j];
        s_f1[tid] = fmaxf(a, 0.f);
    }
    __syncthreads();

    // ---------------- Phase 5: fc2 (50->10) ----------------
    if (tid < 10) {
        const float* wr = fw2 + tid * 50;
        float a = fb2[tid];
        for (int k = 0; k < 50; ++k) a += s_f1[k] * wr[k];
        s_lg[tid] = a;
    }
    __syncthreads();

    // ---------------- Phase 6: log_softmax ----------------
    if (tid < 10) {
        float m = s_lg[0];
        for (int k = 1; k < 10; ++k) m = fmaxf(m, s_lg[k]);
        float s = 0.f;
        for (int k = 0; k < 10; ++k) s += expf(s_lg[k] - m);
        out[(size_t)b * 10 + tid] = s_lg[tid] - m - logf(s);
    }
}

extern "C" void kernel_launch(void* const* d_in, const int* in_sizes, int n_in,
                              void* d_out, int out_size, void* d_ws, size_t ws_size,
                              hipStream_t stream) {
    const float* x   = (const float*)d_in[0];
    const float* W   = (const float*)d_in[1];
    const float* w1  = (const float*)d_in[2];
    const float* b1  = (const float*)d_in[3];
    const float* w2  = (const float*)d_in[4];
    const float* b2  = (const float*)d_in[5];
    const float* fw1 = (const float*)d_in[6];
    const float* fb1 = (const float*)d_in[7];
    const float* fw2 = (const float*)d_in[8];
    const float* fb2 = (const float*)d_in[9];
    float* o = (float*)d_out;

    const int B = in_sizes[0] / 3072;
    fused_net<<<dim3(B), dim3(256), 0, stream>>>(x, W, w1, b1, w2, b2, fw1, fb1, fw2, fb2, o);
}

// Round 5
// 168.224 us; speedup vs baseline: 2.1946x; 1.9526x over previous
//
#include <hip/hip_runtime.h>
#include <math.h>

// Fused net, round 5: MFMA (bf16) for linear + conv1 + conv2 (97% of FLOPs).
// - s_img: HWC4 bf16 (ch padded 3->4, row stride 136 elems) -> conv1 K-dim (kx,ic4) contiguous
// - s_h1 : HWC12 bf16 (ch padded 10->12, row stride 168 elems) -> conv2 K-dim contiguous
// - A-frag = 2x ds_read_b64/lane (split-k layout k = 16*(e>>2)+4*(lane>>4)+(e&3));
//   identical k-formula on A and B sides => any k-permutation mismatch cancels.
// - B-frags prepacked in d_ws by setup kernel; zero rows kill A padding garbage.
// - Quad-ordered M-tiles: C-frag lane rows = one 2x2 pool window -> lane-local maxpool.
// - fc1/fc2/log_softmax unchanged (f32 VALU).

typedef __attribute__((ext_vector_type(8))) short bf16x8;
typedef __attribute__((ext_vector_type(4))) float f32x4;

union Frag { short4 h[2]; bf16x8 v; };

static __device__ __forceinline__ unsigned short f2bf(float f) {
    union { float f; unsigned u; } v; v.f = f;
    unsigned r = v.u + 0x7FFFu + ((v.u >> 16) & 1u);   // RNE
    return (unsigned short)(r >> 16);
}

#define MFMA(a, b, c) __builtin_amdgcn_mfma_f32_16x16x32_bf16((a), (b), (c), 0, 0, 0)

// ---------------- B-fragment prepack: 31 frags x 64 lanes x 8 bf16 ----------------
// fid 0..5  : linear  B[k][j]=W[j][k], fid=ks*3+nt (K=48 -> 2 steps, N=48 -> 3 tiles)
// fid 6..10 : conv1   ky=fid-6; window elem e=kx*4+icp (pixel stride 4)
// fid 11..30: conv2   fid-11 = nt*10+ky*2+s; window elem e=32s+kap, e=kx*12+icp (stride 12)
__global__ __launch_bounds__(64)
void prepack(const float* __restrict__ W, const float* __restrict__ w1,
             const float* __restrict__ w2, unsigned short* __restrict__ ws) {
    const int fid = blockIdx.x;
    const int lane = threadIdx.x;
    const int col = lane & 15, grp = lane >> 4;
    unsigned short tmp[8];
    #pragma unroll
    for (int e = 0; e < 8; ++e) {
        const int kap = 16 * (e >> 2) + 4 * grp + (e & 3);   // 0..31
        float v = 0.f;
        if (fid < 6) {
            const int ks = fid / 3, nt = fid % 3;
            const int k = 32 * ks + kap, j = 16 * nt + col;
            if (k < 48) v = W[j * 48 + k];
        } else if (fid < 11) {
            const int ky = fid - 6;
            const int kx = kap >> 2, icp = kap & 3;
            if (kx < 5 && icp < 3 && col < 10)
                v = w1[col * 75 + icp * 25 + ky * 5 + kx];
        } else {
            const int r = fid - 11, nt = r / 10, ky = (r % 10) >> 1, s = r & 1;
            const int idx = 32 * s + kap;
            const int kx = idx / 12, icp = idx % 12, oc = 16 * nt + col;
            if (kx < 5 && icp < 10 && oc < 20)
                v = w2[oc * 250 + icp * 25 + ky * 5 + kx];
        }
        tmp[e] = f2bf(v);
    }
    Frag f;
    f.h[0] = make_short4((short)tmp[0], (short)tmp[1], (short)tmp[2], (short)tmp[3]);
    f.h[1] = make_short4((short)tmp[4], (short)tmp[5], (short)tmp[6], (short)tmp[7]);
    *(bf16x8*)(ws + fid * 512 + lane * 8) = f.v;
}

// ---------------- main fused kernel: one block (256 thr) per image ----------------
#define RS1 136   // s_img row stride (elems): 32 cols * 4ch + 8 pad
#define RS2 168   // s_h1 row stride (elems): 14 cols * 12ch

__global__ __launch_bounds__(256)
void fused_net(const float* __restrict__ x,    // [B,32,32,3] NHWC f32
               const unsigned short* __restrict__ ws, // prepacked B-frags
               const float* __restrict__ b1,   // [10]
               const float* __restrict__ b2,   // [20]
               const float* __restrict__ fw1,  // [50,500]
               const float* __restrict__ fb1,  // [50]
               const float* __restrict__ fw2,  // [10,50]
               const float* __restrict__ fb2,  // [10]
               float* __restrict__ out)        // [B,10]
{
    const int b    = blockIdx.x;
    const int tid  = threadIdx.x;
    const int wave = __builtin_amdgcn_readfirstlane(tid >> 6);
    const int lane = tid & 63;
    const int col16 = lane & 15, grp = lane >> 4;

    __shared__ unsigned short s_img[32 * RS1 + 64];  // HWC4 bf16 + zeroed tail
    __shared__ unsigned short s_h1[14 * RS2 + 64];   // HWC12 bf16 + zeroed tail
    __shared__ float s_h2[500];
    __shared__ float s_part[256];
    __shared__ float s_f1[56];
    __shared__ float s_lg[16];

    // ---------------- Phase 1: linear via MFMA -> s_img (HWC4 bf16) ----------------
    {
        Frag bl[6];
        #pragma unroll
        for (int f = 0; f < 6; ++f)
            bl[f].v = *(const bf16x8*)(ws + f * 512 + lane * 8);

        // A-frags: lane row m = block 16*wave+m; k-chunks are 4 consecutive x floats.
        const int blkA = 16 * wave + col16;
        const float* xb = x + (size_t)b * 3072 + (blkA >> 3) * 384 + (blkA & 7) * 12;
        const int k0 = 4 * grp,      o0 = (k0 / 12) * 96 + (k0 % 12);
        const int k1 = 16 + 4 * grp, o1 = (k1 / 12) * 96 + (k1 % 12);
        const int k2 = 32 + 4 * grp, o2 = (k2 / 12) * 96 + (k2 % 12);
        const float4 fa = *(const float4*)(xb + o0);
        const float4 fb = *(const float4*)(xb + o1);
        const float4 fc = *(const float4*)(xb + o2);
        Frag a0, a1;
        a0.h[0] = make_short4((short)f2bf(fa.x), (short)f2bf(fa.y), (short)f2bf(fa.z), (short)f2bf(fa.w));
        a0.h[1] = make_short4((short)f2bf(fb.x), (short)f2bf(fb.y), (short)f2bf(fb.z), (short)f2bf(fb.w));
        a1.h[0] = make_short4((short)f2bf(fc.x), (short)f2bf(fc.y), (short)f2bf(fc.z), (short)f2bf(fc.w));
        a1.h[1] = make_short4(0, 0, 0, 0);        // k>=48 pad: zero (also avoids OOB x reads)

        #pragma unroll
        for (int nt = 0; nt < 3; ++nt) {
            f32x4 acc = {0.f, 0.f, 0.f, 0.f};
            acc = MFMA(a0.v, bl[nt].v, acc);
            acc = MFMA(a1.v, bl[3 + nt].v, acc);
            const int j = 16 * nt + col16;                 // output k' index
            const int di = j / 12, dj = (j % 12) / 3, cch = j % 3;
            #pragma unroll
            for (int r = 0; r < 4; ++r) {
                const int blk = 16 * wave + 4 * grp + r;   // C row = block id
                const int row = (blk >> 3) * 4 + di, cp = (blk & 7) * 4 + dj;
                s_img[row * RS1 + cp * 4 + cch] = f2bf(acc[r]);
            }
        }
    }
    // zero pad-channel 3 and LDS tails (A-window overreach reads must be finite)
    for (int p = tid; p < 1024; p += 256)
        s_img[(p >> 5) * RS1 + (p & 31) * 4 + 3] = 0;
    if (tid < 64) s_img[32 * RS1 + tid] = 0;
    if (tid < 64) s_h1[14 * RS2 + tid] = 0;
    __syncthreads();

    // ---------------- Phase 2: conv1+pool+relu via MFMA -> s_h1 (HWC12 bf16) ----------------
    // M = 784 conv pixels in quad order (quad q=(oi,oj) pooled pixel; sub = 2x2 position).
    // 49 M-tiles, 5 K-steps (ky), N=10 (1 tile). Pool = 3 lane-local fmax over C regs.
    {
        Frag bc1[5];
        #pragma unroll
        for (int f = 0; f < 5; ++f)
            bc1[f].v = *(const bf16x8*)(ws + (6 + f) * 512 + lane * 8);
        const float bias1 = b1[col16 < 10 ? col16 : 0];

        for (int t = wave; t < 49; t += 4) {
            const int q = 4 * t + (col16 >> 2), sub = col16 & 3;   // A row m = col16
            const int oi = q / 14, oj = q % 14;
            const int ci = 2 * oi + (sub >> 1), cj = 2 * oj + (sub & 1);
            const int base = ci * RS1 + cj * 4 + 4 * grp;
            f32x4 acc = {0.f, 0.f, 0.f, 0.f};
            #pragma unroll
            for (int ky = 0; ky < 5; ++ky) {
                Frag a;
                a.h[0] = *(const short4*)&s_img[base + ky * RS1];
                a.h[1] = *(const short4*)&s_img[base + ky * RS1 + 16];
                acc = MFMA(a.v, bc1[ky].v, acc);
            }
            const int qo = 4 * t + grp;          // C rows 4*grp..+3 = one pool quad
            if (col16 < 12) {
                const float pm = fmaxf(fmaxf(acc[0], acc[1]), fmaxf(acc[2], acc[3]));
                const float val = fmaxf(pm + bias1, 0.f);
                s_h1[(qo / 14) * RS2 + (qo % 14) * 12 + col16] =
                    (col16 < 10) ? f2bf(val) : (unsigned short)0;
            }
        }
    }
    __syncthreads();

    // ---------------- Phase 3: conv2+pool+relu via MFMA -> s_h2 (f32, flatten order) ----------------
    // M = 100 conv pixels in quad order (25 quads -> 7 M-tiles); 10 K-steps (ky,s); N = 2 tiles.
    {
        Frag b20[10], b21[10];
        #pragma unroll
        for (int f = 0; f < 10; ++f) {
            b20[f].v = *(const bf16x8*)(ws + (11 + f) * 512 + lane * 8);
            b21[f].v = *(const bf16x8*)(ws + (21 + f) * 512 + lane * 8);
        }
        const int oc1 = 16 + col16;
        const float bias20 = b2[col16];                    // col16 <= 15 < 20
        const float bias21 = b2[oc1 < 20 ? oc1 : 0];

        for (int t = wave; t < 7; t += 4) {
            int q = 4 * t + (col16 >> 2); if (q > 24) q = 24;   // clamp garbage rows in-bounds
            const int sub = col16 & 3;
            const int oi = q / 5, oj = q % 5;
            const int ci = 2 * oi + (sub >> 1), cj = 2 * oj + (sub & 1);
            const int base = ci * RS2 + cj * 12 + 4 * grp;
            f32x4 acc0 = {0.f, 0.f, 0.f, 0.f}, acc1 = {0.f, 0.f, 0.f, 0.f};
            #pragma unroll
            for (int ky = 0; ky < 5; ++ky) {
                #pragma unroll
                for (int s = 0; s < 2; ++s) {
                    Frag a;
                    a.h[0] = *(const short4*)&s_h1[base + ky * RS2 + 32 * s];
                    a.h[1] = *(const short4*)&s_h1[base + ky * RS2 + 32 * s + 16];
                    acc0 = MFMA(a.v, b20[ky * 2 + s].v, acc0);
                    acc1 = MFMA(a.v, b21[ky * 2 + s].v, acc1);
                }
            }
            const int qo = 4 * t + grp;
            if (qo < 25) {
                const float p0 = fmaxf(fmaxf(acc0[0], acc0[1]), fmaxf(acc0[2], acc0[3]));
                s_h2[col16 * 25 + qo] = fmaxf(p0 + bias20, 0.f);
                if (oc1 < 20) {
                    const float p1 = fmaxf(fmaxf(acc1[0], acc1[1]), fmaxf(acc1[2], acc1[3]));
                    s_h2[oc1 * 25 + qo] = fmaxf(p1 + bias21, 0.f);
                }
            }
        }
    }
    __syncthreads();

    // ---------------- Phase 4: fc1 (500->50) split 5-way + relu ----------------
    if (tid < 250) {
        const int oc = tid / 5, part = tid % 5;
        const float* wr = fw1 + oc * 500 + part * 100;
        const float* hp = s_h2 + part * 100;
        float a = 0.f;
        #pragma unroll
        for (int i = 0; i < 25; ++i) {
            const float4 wv = *reinterpret_cast<const float4*>(wr + i * 4);
            const float4 hv = *reinterpret_cast<const float4*>(hp + i * 4);
            a += wv.x * hv.x + wv.y * hv.y + wv.z * hv.z + wv.w * hv.w;
        }
        s_part[tid] = a;
    }
    __syncthreads();
    if (tid < 50) {
        float a = fb1[tid];
        #pragma unroll
        for (int j = 0; j < 5; ++j) a += s_part[tid * 5 + j];
        s_f1[tid] = fmaxf(a, 0.f);
    }
    __syncthreads();

    // ---------------- Phase 5: fc2 (50->10) ----------------
    if (tid < 10) {
        const float* wr = fw2 + tid * 50;
        float a = fb2[tid];
        for (int k = 0; k < 50; ++k) a += s_f1[k] * wr[k];
        s_lg[tid] = a;
    }
    __syncthreads();

    // ---------------- Phase 6: log_softmax ----------------
    if (tid < 10) {
        float m = s_lg[0];
        for (int k = 1; k < 10; ++k) m = fmaxf(m, s_lg[k]);
        float s = 0.f;
        for (int k = 0; k < 10; ++k) s += expf(s_lg[k] - m);
        out[(size_t)b * 10 + tid] = s_lg[tid] - m - logf(s);
    }
}

extern "C" void kernel_launch(void* const* d_in, const int* in_sizes, int n_in,
                              void* d_out, int out_size, void* d_ws, size_t ws_size,
                              hipStream_t stream) {
    const float* x   = (const float*)d_in[0];
    const float* W   = (const float*)d_in[1];
    const float* w1  = (const float*)d_in[2];
    const float* b1  = (const float*)d_in[3];
    const float* w2  = (const float*)d_in[4];
    const float* b2  = (const float*)d_in[5];
    const float* fw1 = (const float*)d_in[6];
    const float* fb1 = (const float*)d_in[7];
    const float* fw2 = (const float*)d_in[8];
    const float* fb2 = (const float*)d_in[9];
    float* o = (float*)d_out;
    unsigned short* wsp = (unsigned short*)d_ws;

    const int B = in_sizes[0] / 3072;
    prepack<<<dim3(31), dim3(64), 0, stream>>>(W, w1, w2, wsp);
    fused_net<<<dim3(B), dim3(256), 0, stream>>>(x, wsp, b1, b2, fw1, fb1, fw2, fb2, o);
}

// Round 7
// 167.988 us; speedup vs baseline: 2.1977x; 1.0014x over previous
//
#include <hip/hip_runtime.h>
#include <math.h>

// Fused net, round 7: round-5 structure, three changes:
//  (a) B-frags streamed from L2 inside the loops (phase 1: per-nt, phase 3: per-ky/s)
//      instead of held resident -> peak live VGPRs drop below the 64 occupancy boundary
//      structurally (round 6 showed capping via __launch_bounds__(256,8) just spills).
//  (b) s_img row-pad columns 128..135 explicitly zeroed -> no code path reads
//      uninitialized LDS (round 6's call-to-call absmax drift pointed here).
//  (c) __launch_bounds__(256) with no min-waves clause (proven-safe allocator mode).

typedef __attribute__((ext_vector_type(8))) short bf16x8;
typedef __attribute__((ext_vector_type(4))) float f32x4;

union Frag { short4 h[2]; bf16x8 v; };

static __device__ __forceinline__ unsigned short f2bf(float f) {
    union { float f; unsigned u; } v; v.f = f;
    unsigned r = v.u + 0x7FFFu + ((v.u >> 16) & 1u);   // RNE
    return (unsigned short)(r >> 16);
}

#define MFMA(a, b, c) __builtin_amdgcn_mfma_f32_16x16x32_bf16((a), (b), (c), 0, 0, 0)

// ---------------- B-fragment prepack: 31 frags x 64 lanes x 8 bf16 ----------------
// fid 0..5  : linear  B[k][j]=W[j][k], fid=ks*3+nt (K=48 -> 2 steps, N=48 -> 3 tiles)
// fid 6..10 : conv1   ky=fid-6; window elem e=kx*4+icp (pixel stride 4)
// fid 11..30: conv2   fid-11 = nt*10+ky*2+s; window elem idx=32s+kap, idx=kx*12+icp
__global__ __launch_bounds__(64)
void prepack(const float* __restrict__ W, const float* __restrict__ w1,
             const float* __restrict__ w2, unsigned short* __restrict__ ws) {
    const int fid = blockIdx.x;
    const int lane = threadIdx.x;
    const int col = lane & 15, grp = lane >> 4;
    unsigned short tmp[8];
    #pragma unroll
    for (int e = 0; e < 8; ++e) {
        const int kap = 16 * (e >> 2) + 4 * grp + (e & 3);   // 0..31
        float v = 0.f;
        if (fid < 6) {
            const int ks = fid / 3, nt = fid % 3;
            const int k = 32 * ks + kap, j = 16 * nt + col;
            if (k < 48) v = W[j * 48 + k];
        } else if (fid < 11) {
            const int ky = fid - 6;
            const int kx = kap >> 2, icp = kap & 3;
            if (kx < 5 && icp < 3 && col < 10)
                v = w1[col * 75 + icp * 25 + ky * 5 + kx];
        } else {
            const int r = fid - 11, nt = r / 10, ky = (r % 10) >> 1, s = r & 1;
            const int idx = 32 * s + kap;
            const int kx = idx / 12, icp = idx % 12, oc = 16 * nt + col;
            if (kx < 5 && icp < 10 && oc < 20)
                v = w2[oc * 250 + icp * 25 + ky * 5 + kx];
        }
        tmp[e] = f2bf(v);
    }
    Frag f;
    f.h[0] = make_short4((short)tmp[0], (short)tmp[1], (short)tmp[2], (short)tmp[3]);
    f.h[1] = make_short4((short)tmp[4], (short)tmp[5], (short)tmp[6], (short)tmp[7]);
    *(bf16x8*)(ws + fid * 512 + lane * 8) = f.v;
}

// ---------------- main fused kernel: one block (256 thr) per image ----------------
#define RS1 136   // s_img row stride (elems): 32 cols * 4ch + 8 pad
#define RS2 168   // s_h1 row stride (elems): 14 cols * 12ch

__global__ __launch_bounds__(256)
void fused_net(const float* __restrict__ x,    // [B,32,32,3] NHWC f32
               const unsigned short* __restrict__ ws, // prepacked B-frags
               const float* __restrict__ b1,   // [10]
               const float* __restrict__ b2,   // [20]
               const float* __restrict__ fw1,  // [50,500]
               const float* __restrict__ fb1,  // [50]
               const float* __restrict__ fw2,  // [10,50]
               const float* __restrict__ fb2,  // [10]
               float* __restrict__ out)        // [B,10]
{
    const int b    = blockIdx.x;
    const int tid  = threadIdx.x;
    const int wave = __builtin_amdgcn_readfirstlane(tid >> 6);
    const int lane = tid & 63;
    const int col16 = lane & 15, grp = lane >> 4;

    __shared__ unsigned short s_img[32 * RS1 + 64];  // HWC4 bf16 + zeroed pads/tail
    __shared__ unsigned short s_h1[14 * RS2 + 64];   // HWC12 bf16 + zeroed tail
    __shared__ float s_h2[500];
    __shared__ float s_part[256];
    __shared__ float s_f1[56];
    __shared__ float s_lg[16];

    // ---------------- Phase 1: linear via MFMA -> s_img (HWC4 bf16) ----------------
    {
        const int blkA = 16 * wave + col16;
        const float* xb = x + (size_t)b * 3072 + (blkA >> 3) * 384 + (blkA & 7) * 12;
        const int k0 = 4 * grp,      o0 = (k0 / 12) * 96 + (k0 % 12);
        const int k1 = 16 + 4 * grp, o1 = (k1 / 12) * 96 + (k1 % 12);
        const int k2 = 32 + 4 * grp, o2 = (k2 / 12) * 96 + (k2 % 12);
        const float4 fa = *(const float4*)(xb + o0);
        const float4 fb = *(const float4*)(xb + o1);
        const float4 fc = *(const float4*)(xb + o2);
        Frag a0, a1;
        a0.h[0] = make_short4((short)f2bf(fa.x), (short)f2bf(fa.y), (short)f2bf(fa.z), (short)f2bf(fa.w));
        a0.h[1] = make_short4((short)f2bf(fb.x), (short)f2bf(fb.y), (short)f2bf(fb.z), (short)f2bf(fb.w));
        a1.h[0] = make_short4((short)f2bf(fc.x), (short)f2bf(fc.y), (short)f2bf(fc.z), (short)f2bf(fc.w));
        a1.h[1] = make_short4(0, 0, 0, 0);        // k>=48 pad: zero (also avoids OOB x reads)

        #pragma unroll
        for (int nt = 0; nt < 3; ++nt) {
            Frag bl0, bl1;                        // streamed from L2, not resident
            bl0.v = *(const bf16x8*)(ws + nt * 512 + lane * 8);
            bl1.v = *(const bf16x8*)(ws + (3 + nt) * 512 + lane * 8);
            f32x4 acc = {0.f, 0.f, 0.f, 0.f};
            acc = MFMA(a0.v, bl0.v, acc);
            acc = MFMA(a1.v, bl1.v, acc);
            const int j = 16 * nt + col16;                 // output k' index
            const int di = j / 12, dj = (j % 12) / 3, cch = j % 3;
            #pragma unroll
            for (int r = 0; r < 4; ++r) {
                const int blk = 16 * wave + 4 * grp + r;   // C row = block id
                const int row = (blk >> 3) * 4 + di, cp = (blk & 7) * 4 + dj;
                s_img[row * RS1 + cp * 4 + cch] = f2bf(acc[r]);
            }
        }
    }
    // zero pad-channel 3, row pads (cols 128..135), and LDS tails: no uninit reads ever
    for (int p = tid; p < 1024; p += 256)
        s_img[(p >> 5) * RS1 + (p & 31) * 4 + 3] = 0;
    if (tid < 256) s_img[(tid >> 3) * RS1 + 128 + (tid & 7)] = 0;
    if (tid < 64) s_img[32 * RS1 + tid] = 0;
    if (tid < 64) s_h1[14 * RS2 + tid] = 0;
    __syncthreads();

    // ---------------- Phase 2: conv1+pool+relu via MFMA -> s_h1 (HWC12 bf16) ----------------
    // M = 784 conv pixels in quad order; 49 M-tiles, 5 K-steps (ky), N=10 (1 tile).
    {
        Frag bc1[5];                              // resident: phase-2 peak is ~48 VGPR
        #pragma unroll
        for (int f = 0; f < 5; ++f)
            bc1[f].v = *(const bf16x8*)(ws + (6 + f) * 512 + lane * 8);
        const float bias1 = b1[col16 < 10 ? col16 : 0];

        for (int t = wave; t < 49; t += 4) {
            const int q = 4 * t + (col16 >> 2), sub = col16 & 3;   // A row m = col16
            const int oi = q / 14, oj = q % 14;
            const int ci = 2 * oi + (sub >> 1), cj = 2 * oj + (sub & 1);
            const int base = ci * RS1 + cj * 4 + 4 * grp;
            f32x4 acc = {0.f, 0.f, 0.f, 0.f};
            #pragma unroll
            for (int ky = 0; ky < 5; ++ky) {
                Frag a;
                a.h[0] = *(const short4*)&s_img[base + ky * RS1];
                a.h[1] = *(const short4*)&s_img[base + ky * RS1 + 16];
                acc = MFMA(a.v, bc1[ky].v, acc);
            }
            const int qo = 4 * t + grp;          // C rows 4*grp..+3 = one pool quad
            if (col16 < 12) {
                const float pm = fmaxf(fmaxf(acc[0], acc[1]), fmaxf(acc[2], acc[3]));
                const float val = fmaxf(pm + bias1, 0.f);
                s_h1[(qo / 14) * RS2 + (qo % 14) * 12 + col16] =
                    (col16 < 10) ? f2bf(val) : (unsigned short)0;
            }
        }
    }
    __syncthreads();

    // ---------------- Phase 3: conv2+pool+relu via MFMA -> s_h2 (f32, flatten order) ----------------
    // M = 100 conv pixels in quad order (25 quads -> 7 M-tiles); 10 K-steps; N = 2 tiles.
    // B-frags streamed per K-step (L2-hot, 16B/lane) -> only 2 frags live at a time.
    {
        const int oc1 = 16 + col16;
        const float bias20 = b2[col16];                    // col16 <= 15 < 20
        const float bias21 = b2[oc1 < 20 ? oc1 : 0];

        for (int t = wave; t < 7; t += 4) {
            int q = 4 * t + (col16 >> 2); if (q > 24) q = 24;   // clamp garbage rows in-bounds
            const int sub = col16 & 3;
            const int oi = q / 5, oj = q % 5;
            const int ci = 2 * oi + (sub >> 1), cj = 2 * oj + (sub & 1);
            const int base = ci * RS2 + cj * 12 + 4 * grp;
            f32x4 acc0 = {0.f, 0.f, 0.f, 0.f}, acc1 = {0.f, 0.f, 0.f, 0.f};
            #pragma unroll
            for (int ky = 0; ky < 5; ++ky) {
                #pragma unroll
                for (int s = 0; s < 2; ++s) {
                    Frag a, bb0, bb1;
                    a.h[0] = *(const short4*)&s_h1[base + ky * RS2 + 32 * s];
                    a.h[1] = *(const short4*)&s_h1[base + ky * RS2 + 32 * s + 16];
                    bb0.v = *(const bf16x8*)(ws + (11 + ky * 2 + s) * 512 + lane * 8);
                    bb1.v = *(const bf16x8*)(ws + (21 + ky * 2 + s) * 512 + lane * 8);
                    acc0 = MFMA(a.v, bb0.v, acc0);
                    acc1 = MFMA(a.v, bb1.v, acc1);
                }
            }
            const int qo = 4 * t + grp;
            if (qo < 25) {
                const float p0 = fmaxf(fmaxf(acc0[0], acc0[1]), fmaxf(acc0[2], acc0[3]));
                s_h2[col16 * 25 + qo] = fmaxf(p0 + bias20, 0.f);
                if (oc1 < 20) {
                    const float p1 = fmaxf(fmaxf(acc1[0], acc1[1]), fmaxf(acc1[2], acc1[3]));
                    s_h2[oc1 * 25 + qo] = fmaxf(p1 + bias21, 0.f);
                }
            }
        }
    }
    __syncthreads();

    // ---------------- Phase 4: fc1 (500->50) split 5-way + relu ----------------
    if (tid < 250) {
        const int oc = tid / 5, part = tid % 5;
        const float* wr = fw1 + oc * 500 + part * 100;
        const float* hp = s_h2 + part * 100;
        float a = 0.f;
        #pragma unroll
        for (int i = 0; i < 25; ++i) {
            const float4 wv = *reinterpret_cast<const float4*>(wr + i * 4);
            const float4 hv = *reinterpret_cast<const float4*>(hp + i * 4);
            a += wv.x * hv.x + wv.y * hv.y + wv.z * hv.z + wv.w * hv.w;
        }
        s_part[tid] = a;
    }
    __syncthreads();
    if (tid < 50) {
        float a = fb1[tid];
        #pragma unroll
        for (int j = 0; j < 5; ++j) a += s_part[tid * 5 + j];
        s_f1[tid] = fmaxf(a, 0.f);
    }
    __syncthreads();

    // ---------------- Phase 5: fc2 (50->10) ----------------
    if (tid < 10) {
        const float* wr = fw2 + tid * 50;
        float a = fb2[tid];
        for (int k = 0; k < 50; ++k) a += s_f1[k] * wr[k];
        s_lg[tid] = a;
    }
    __syncthreads();

    // ---------------- Phase 6: log_softmax ----------------
    if (tid < 10) {
        float m = s_lg[0];
        for (int k = 1; k < 10; ++k) m = fmaxf(m, s_lg[k]);
        float s = 0.f;
        for (int k = 0; k < 10; ++k) s += expf(s_lg[k] - m);
        out[(size_t)b * 10 + tid] = s_lg[tid] - m - logf(s);
    }
}

extern "C" void kernel_launch(void* const* d_in, const int* in_sizes, int n_in,
                              void* d_out, int out_size, void* d_ws, size_t ws_size,
                              hipStream_t stream) {
    const float* x   = (const float*)d_in[0];
    const float* W   = (const float*)d_in[1];
    const float* w1  = (const float*)d_in[2];
    const float* b1  = (const float*)d_in[3];
    const float* w2  = (const float*)d_in[4];
    const float* b2  = (const float*)d_in[5];
    const float* fw1 = (const float*)d_in[6];
    const float* fb1 = (const float*)d_in[7];
    const float* fw2 = (const float*)d_in[8];
    const float* fb2 = (const float*)d_in[9];
    float* o = (float*)d_out;
    unsigned short* wsp = (unsigned short*)d_ws;

    const int B = in_sizes[0] / 3072;
    prepack<<<dim3(31), dim3(64), 0, stream>>>(W, w1, w2, wsp);
    fused_net<<<dim3(B), dim3(256), 0, stream>>>(x, wsp, b1, b2, fw1, fb1, fw2, fb2, o);
}